// Round 4
// baseline (249.378 us; speedup 1.0000x reference)
//
#include <hip/hip_runtime.h>
#include <math.h>

#define BN 512
#define ND 256
#define EH 128

typedef __attribute__((ext_vector_type(8))) short short8v;
typedef __attribute__((ext_vector_type(4))) float f32x4;

__device__ __forceinline__ unsigned short f2bf_rn(float x) {
  unsigned int u = __float_as_uint(x);
  unsigned int r = u + 0x7FFFu + ((u >> 16) & 1u);
  return (unsigned short)(r >> 16);
}
__device__ __forceinline__ float bf2f(unsigned short h) {
  return __uint_as_float(((unsigned int)h) << 16);
}

// -------------------- Kernel A: LN + projections + tgt bf16 --------------------
// grid 256 blocks x 256 thr, 4 rows each.
// ws: srcg f32[1024][128], apreg f32[1024][128] (=src@Ws^T+b1), tgtb u16[1024][128]
__global__ __launch_bounds__(256) void prep_kernel(
    const float* __restrict__ latent,
    const float* __restrict__ sng, const float* __restrict__ snb,
    const float* __restrict__ tng, const float* __restrict__ tnb,
    const float* __restrict__ sW,  const float* __restrict__ sb,
    const float* __restrict__ tW,  const float* __restrict__ tbv,
    const float* __restrict__ W1,  const float* __restrict__ b1,
    float* __restrict__ srcg, float* __restrict__ apreg,
    unsigned short* __restrict__ tgtb)
{
  __shared__ float lns[4][256];
  __shared__ float lnt[4][256];
  __shared__ float ssrc[4][128];
  const int tid = threadIdx.x;
  const int w = tid >> 6, lane = tid & 63;
  const int row0 = blockIdx.x << 2;

  // phase 1: LN (one wave per row)
  {
    const int row = row0 + w;
    const float* x = latent + (size_t)row * ND;
    const int h = lane << 2;
    float4 xv = *(const float4*)(x + h);
    float s1 = xv.x + xv.y + xv.z + xv.w;
    float s2 = xv.x*xv.x + xv.y*xv.y + xv.z*xv.z + xv.w*xv.w;
    #pragma unroll
    for (int m = 1; m < 64; m <<= 1) {
      s1 += __shfl_xor(s1, m, 64);
      s2 += __shfl_xor(s2, m, 64);
    }
    const float mu  = s1 * (1.0f/256.0f);
    const float var = s2 * (1.0f/256.0f) - mu*mu;
    const float rstd = rsqrtf(var + 1e-5f);
    float4 ga = *(const float4*)(sng + h), ba = *(const float4*)(snb + h);
    float4 gb = *(const float4*)(tng + h), bb = *(const float4*)(tnb + h);
    const float n0 = (xv.x - mu)*rstd, n1 = (xv.y - mu)*rstd;
    const float n2 = (xv.z - mu)*rstd, n3 = (xv.w - mu)*rstd;
    lns[w][h+0] = n0*ga.x + ba.x; lns[w][h+1] = n1*ga.y + ba.y;
    lns[w][h+2] = n2*ga.z + ba.z; lns[w][h+3] = n3*ga.w + ba.w;
    lnt[w][h+0] = n0*gb.x + bb.x; lnt[w][h+1] = n1*gb.y + bb.y;
    lnt[w][h+2] = n2*gb.z + bb.z; lnt[w][h+3] = n3*gb.w + bb.w;
  }
  __syncthreads();

  const int side = tid >> 7, k = tid & 127;
  // phase 2: src = lns@sW^T+sb (side 0, f32) ; tgt = lnt@tW^T+tb (side 1, bf16 rn)
  {
    const float* W = side ? tW : sW;
    const float bias = side ? tbv[k] : sb[k];
    const float (*L)[256] = side ? lnt : lns;
    float a0 = bias, a1 = bias, a2 = bias, a3 = bias;
    const float* wr = W + (size_t)k * ND;
    for (int h4 = 0; h4 < ND; h4 += 4) {
      float4 wv = *(const float4*)(wr + h4);
      float4 l0 = *(const float4*)&L[0][h4];
      float4 l1 = *(const float4*)&L[1][h4];
      float4 l2 = *(const float4*)&L[2][h4];
      float4 l3 = *(const float4*)&L[3][h4];
      a0 += wv.x*l0.x + wv.y*l0.y + wv.z*l0.z + wv.w*l0.w;
      a1 += wv.x*l1.x + wv.y*l1.y + wv.z*l1.z + wv.w*l1.w;
      a2 += wv.x*l2.x + wv.y*l2.y + wv.z*l2.z + wv.w*l2.w;
      a3 += wv.x*l3.x + wv.y*l3.y + wv.z*l3.z + wv.w*l3.w;
    }
    if (!side) {
      ssrc[0][k]=a0; ssrc[1][k]=a1; ssrc[2][k]=a2; ssrc[3][k]=a3;
      srcg[(size_t)(row0+0)*EH+k]=a0; srcg[(size_t)(row0+1)*EH+k]=a1;
      srcg[(size_t)(row0+2)*EH+k]=a2; srcg[(size_t)(row0+3)*EH+k]=a3;
    } else {
      tgtb[(size_t)(row0+0)*EH + k] = f2bf_rn(a0);
      tgtb[(size_t)(row0+1)*EH + k] = f2bf_rn(a1);
      tgtb[(size_t)(row0+2)*EH + k] = f2bf_rn(a2);
      tgtb[(size_t)(row0+3)*EH + k] = f2bf_rn(a3);
    }
  }
  __syncthreads();

  // phase 3: Apre = src@Ws^T + b1   (Ws = W1[:, :128]); 256 threads, 2 rows each
  {
    const int kk = tid & 127, half = tid >> 7;
    const float bb = b1[kk];
    float a0 = bb, a1 = bb;
    const float* wr = W1 + (size_t)kk * 384;
    const int r0 = half * 2;
    for (int h4 = 0; h4 < EH; h4 += 4) {
      float4 wv = *(const float4*)(wr + h4);
      float4 l0 = *(const float4*)&ssrc[r0][h4];
      float4 l1 = *(const float4*)&ssrc[r0+1][h4];
      a0 += wv.x*l0.x + wv.y*l0.y + wv.z*l0.z + wv.w*l0.w;
      a1 += wv.x*l1.x + wv.y*l1.y + wv.z*l1.z + wv.w*l1.w;
    }
    apreg[(size_t)(row0+r0)*EH + kk]   = a0;
    apreg[(size_t)(row0+r0+1)*EH + kk] = a1;
  }
}

// -------------------- Kernel B: per-(b,i) MFMA edge row --------------------
// grid 1024 = (b,i), 256 thr = 4 waves, 4 blocks/CU (LDS 33KB), 4 waves/SIMD target.
// G'[k][h] = src_i[h]*Wp[k][h] + Wt[k][h], single rn bf16 in swizzled LDS.
// h = tgt @ G'^T + Apre (folded into acc init); tanh-gelu; <W2,g>; softsign; diag=0.
__global__ __launch_bounds__(256, 4) void edge_kernel(
    const float* __restrict__ srcg, const float* __restrict__ apreg,
    const unsigned short* __restrict__ tgtb,
    const float* __restrict__ W1, const float* __restrict__ W2,
    const float* __restrict__ b2, float* __restrict__ out)
{
  __shared__ __align__(16) unsigned short Gs[128 * 128]; // [k][h] swizzled, 32KB
  __shared__ float s_src[128];

  const int tid = threadIdx.x;
  const int l = tid & 63, w = tid >> 6;
  const int blk = blockIdx.x;
  const int b = blk >> 9, i = blk & 511;

  if (tid < 128) s_src[tid] = srcg[(size_t)blk * EH + tid];
  __syncthreads();

  // ---- stage G' (rn bf16, XOR-swizzled rows) ----
  {
    const int k = tid >> 1, h0 = (tid & 1) * 64;
    const float* wpr = W1 + (size_t)k * 384 + 256 + h0;
    const float* wtr = W1 + (size_t)k * 384 + 128 + h0;
    const unsigned int swz = (unsigned int)((k & 15) << 4);
    char* gB = (char*)Gs + k * 256;
    #pragma unroll
    for (int c = 0; c < 64; c += 8) {
      float4 wpa = *(const float4*)(wpr + c);
      float4 wpb = *(const float4*)(wpr + c + 4);
      float4 wta = *(const float4*)(wtr + c);
      float4 wtb = *(const float4*)(wtr + c + 4);
      float4 sa  = *(const float4*)&s_src[h0 + c];
      float4 sb4 = *(const float4*)&s_src[h0 + c + 4];
      short8v hv;
      hv[0] = (short)f2bf_rn(fmaf(sa.x,  wpa.x, wta.x));
      hv[1] = (short)f2bf_rn(fmaf(sa.y,  wpa.y, wta.y));
      hv[2] = (short)f2bf_rn(fmaf(sa.z,  wpa.z, wta.z));
      hv[3] = (short)f2bf_rn(fmaf(sa.w,  wpa.w, wta.w));
      hv[4] = (short)f2bf_rn(fmaf(sb4.x, wpb.x, wtb.x));
      hv[5] = (short)f2bf_rn(fmaf(sb4.y, wpb.y, wtb.y));
      hv[6] = (short)f2bf_rn(fmaf(sb4.z, wpb.z, wtb.z));
      hv[7] = (short)f2bf_rn(fmaf(sb4.w, wpb.w, wtb.w));
      const unsigned int off = ((unsigned int)((h0 + c) * 2)) ^ swz;
      *(short8v*)(gB + off) = hv;
    }
  }
  __syncthreads();

  // per-lane constants: k-column = nt*16 + (l&15)
  const int l15 = l & 15;
  const int hi4 = l >> 4;           // 0..3
  float apv[8], w2v[8];
  #pragma unroll
  for (int nt = 0; nt < 8; ++nt) {
    apv[nt] = apreg[(size_t)blk * EH + nt * 16 + l15];
    w2v[nt] = W2[nt * 16 + l15];
  }
  const float b2s = b2[0];

  const unsigned short* tB = tgtb + (size_t)b * BN * EH;
  float* orow = out + (size_t)blk * BN;

  const int cb = hi4 * 16;          // byte col base within row for B frags
  const unsigned int swzl = (unsigned int)(l15 << 4);

#define LOADA(buf, ks_)                                                        \
  {                                                                            \
    _Pragma("unroll")                                                          \
    for (int m = 0; m < 2; ++m) {                                              \
      const size_t r = (size_t)(jt0 + m * 16 + l15) * EH + (ks_) * 32 + hi4 * 8;\
      buf[m] = *(const short8v*)(tB + r);                                      \
    }                                                                          \
  }

#define MFMA_STEP(buf, ks_)                                                    \
  {                                                                            \
    _Pragma("unroll")                                                          \
    for (int nt = 0; nt < 8; ++nt) {                                           \
      const int rowoff = nt * 4096 + l15 * 256;                                \
      const unsigned int col = ((unsigned int)(((ks_) << 6) | cb)) ^ swzl;     \
      short8v bfr = *(const short8v*)((const char*)Gs + rowoff + col);         \
      _Pragma("unroll")                                                        \
      for (int m = 0; m < 2; ++m)                                              \
        acc[m][nt] = __builtin_amdgcn_mfma_f32_16x16x32_bf16(buf[m], bfr, acc[m][nt], 0, 0, 0); \
    }                                                                          \
  }

  // 4 passes; wave w, pass p covers j-tiles {p*8 + w*2, p*8 + w*2 + 1}
  #pragma unroll 1
  for (int p = 0; p < 4; ++p) {
    const int jt0 = (p * 8 + w * 2) * 16;
    f32x4 acc[2][8];
    #pragma unroll
    for (int m = 0; m < 2; ++m)
      #pragma unroll
      for (int nt = 0; nt < 8; ++nt)
        acc[m][nt] = (f32x4){apv[nt], apv[nt], apv[nt], apv[nt]};  // bias folded in

    short8v aA[2], aB[2];
    LOADA(aA, 0)
    LOADA(aB, 1)
    MFMA_STEP(aA, 0)
    LOADA(aA, 2)
    MFMA_STEP(aB, 1)
    LOADA(aB, 3)
    MFMA_STEP(aA, 2)
    MFMA_STEP(aB, 3)

    // ---- epilogue: tanh-gelu + W2 dot + softsign ----
    #pragma unroll
    for (int m = 0; m < 2; ++m) {
      float ov[4];
      #pragma unroll
      for (int reg = 0; reg < 4; ++reg) {
        float ps = 0.0f;
        #pragma unroll
        for (int nt = 0; nt < 8; ++nt) {
          const float x  = acc[m][nt][reg];
          const float x2 = x * x;
          // gelu(x) = x * sigmoid(1.5957691x + 0.0713548x^3); exp2-folded consts
          const float q   = fmaf(x2, -0.10294817f, -2.3022077f);
          const float e   = __builtin_amdgcn_exp2f(x * q);
          const float r   = __builtin_amdgcn_rcpf(1.0f + e);
          ps = fmaf(w2v[nt], x * r, ps);
        }
        ps += __shfl_xor(ps, 1, 64);
        ps += __shfl_xor(ps, 2, 64);
        ps += __shfl_xor(ps, 4, 64);
        ps += __shfl_xor(ps, 8, 64);
        const float s = ps + b2s;
        ov[reg] = s / (1.0f + fabsf(s));
      }
      if (l15 == 0) {
        const int j0 = jt0 + m * 16 + hi4 * 4;
        float4 o4 = {(j0 + 0 == i) ? 0.0f : ov[0],
                     (j0 + 1 == i) ? 0.0f : ov[1],
                     (j0 + 2 == i) ? 0.0f : ov[2],
                     (j0 + 3 == i) ? 0.0f : ov[3]};
        *(float4*)(orow + j0) = o4;
      }
    }
  }
#undef LOADA
#undef MFMA_STEP
}

// -------------------- launch --------------------
extern "C" void kernel_launch(void* const* d_in, const int* in_sizes, int n_in,
                              void* d_out, int out_size, void* d_ws, size_t ws_size,
                              hipStream_t stream) {
  const float* latent = (const float*)d_in[0];
  const float* sng = (const float*)d_in[1];
  const float* snb = (const float*)d_in[2];
  const float* tng = (const float*)d_in[3];
  const float* tnb = (const float*)d_in[4];
  const float* sW  = (const float*)d_in[5];
  const float* sb  = (const float*)d_in[6];
  const float* tW  = (const float*)d_in[7];
  const float* tb  = (const float*)d_in[8];
  const float* W1  = (const float*)d_in[9];
  const float* b1  = (const float*)d_in[10];
  const float* W2  = (const float*)d_in[11];
  const float* b2  = (const float*)d_in[12];
  float* out = (float*)d_out;

  float* ws = (float*)d_ws;
  float* srcg  = ws;                                      // [1024][128] f32
  float* apreg = ws + 131072;                             // [1024][128] f32
  unsigned short* tgtb = (unsigned short*)(ws + 262144);  // [1024][128] u16

  hipLaunchKernelGGL(prep_kernel, dim3(256), dim3(256), 0, stream,
                     latent, sng, snb, tng, tnb, sW, sb, tW, tb, W1, b1,
                     srcg, apreg, tgtb);
  hipLaunchKernelGGL(edge_kernel, dim3(1024), dim3(256), 0, stream,
                     srcg, apreg, tgtb, W1, W2, b2, out);
}

// Round 5
// 68.931 us; speedup vs baseline: 3.6178x; 3.6178x over previous
//
#include <hip/hip_runtime.h>
#include <math.h>

#define BN 512
#define ND 256
#define EH 128

typedef __attribute__((ext_vector_type(8))) short short8v;
typedef __attribute__((ext_vector_type(4))) float f32x4;

__device__ __forceinline__ unsigned short f2bf_rn(float x) {
  unsigned int u = __float_as_uint(x);
  unsigned int r = u + 0x7FFFu + ((u >> 16) & 1u);
  return (unsigned short)(r >> 16);
}
__device__ __forceinline__ float bf2f(unsigned short h) {
  return __uint_as_float(((unsigned int)h) << 16);
}

// -------------------- Kernel A: LN + projections + tgt bf16 --------------------
// grid 256 blocks x 256 thr, 4 rows each.
// ws: srcg f32[1024][128], apreg f32[1024][128] (=src@Ws^T+b1), tgtb u16[1024][128]
__global__ __launch_bounds__(256) void prep_kernel(
    const float* __restrict__ latent,
    const float* __restrict__ sng, const float* __restrict__ snb,
    const float* __restrict__ tng, const float* __restrict__ tnb,
    const float* __restrict__ sW,  const float* __restrict__ sb,
    const float* __restrict__ tW,  const float* __restrict__ tbv,
    const float* __restrict__ W1,  const float* __restrict__ b1,
    float* __restrict__ srcg, float* __restrict__ apreg,
    unsigned short* __restrict__ tgtb)
{
  __shared__ float lns[4][256];
  __shared__ float lnt[4][256];
  __shared__ float ssrc[4][128];
  const int tid = threadIdx.x;
  const int w = tid >> 6, lane = tid & 63;
  const int row0 = blockIdx.x << 2;

  // phase 1: LN (one wave per row)
  {
    const int row = row0 + w;
    const float* x = latent + (size_t)row * ND;
    const int h = lane << 2;
    float4 xv = *(const float4*)(x + h);
    float s1 = xv.x + xv.y + xv.z + xv.w;
    float s2 = xv.x*xv.x + xv.y*xv.y + xv.z*xv.z + xv.w*xv.w;
    #pragma unroll
    for (int m = 1; m < 64; m <<= 1) {
      s1 += __shfl_xor(s1, m, 64);
      s2 += __shfl_xor(s2, m, 64);
    }
    const float mu  = s1 * (1.0f/256.0f);
    const float var = s2 * (1.0f/256.0f) - mu*mu;
    const float rstd = rsqrtf(var + 1e-5f);
    float4 ga = *(const float4*)(sng + h), ba = *(const float4*)(snb + h);
    float4 gb = *(const float4*)(tng + h), bb = *(const float4*)(tnb + h);
    const float n0 = (xv.x - mu)*rstd, n1 = (xv.y - mu)*rstd;
    const float n2 = (xv.z - mu)*rstd, n3 = (xv.w - mu)*rstd;
    lns[w][h+0] = n0*ga.x + ba.x; lns[w][h+1] = n1*ga.y + ba.y;
    lns[w][h+2] = n2*ga.z + ba.z; lns[w][h+3] = n3*ga.w + ba.w;
    lnt[w][h+0] = n0*gb.x + bb.x; lnt[w][h+1] = n1*gb.y + bb.y;
    lnt[w][h+2] = n2*gb.z + bb.z; lnt[w][h+3] = n3*gb.w + bb.w;
  }
  __syncthreads();

  const int side = tid >> 7, k = tid & 127;
  // phase 2: src = lns@sW^T+sb (side 0, f32) ; tgt = lnt@tW^T+tb (side 1, bf16 rn)
  {
    const float* W = side ? tW : sW;
    const float bias = side ? tbv[k] : sb[k];
    const float (*L)[256] = side ? lnt : lns;
    float a0 = bias, a1 = bias, a2 = bias, a3 = bias;
    const float* wr = W + (size_t)k * ND;
    for (int h4 = 0; h4 < ND; h4 += 4) {
      float4 wv = *(const float4*)(wr + h4);
      float4 l0 = *(const float4*)&L[0][h4];
      float4 l1 = *(const float4*)&L[1][h4];
      float4 l2 = *(const float4*)&L[2][h4];
      float4 l3 = *(const float4*)&L[3][h4];
      a0 += wv.x*l0.x + wv.y*l0.y + wv.z*l0.z + wv.w*l0.w;
      a1 += wv.x*l1.x + wv.y*l1.y + wv.z*l1.z + wv.w*l1.w;
      a2 += wv.x*l2.x + wv.y*l2.y + wv.z*l2.z + wv.w*l2.w;
      a3 += wv.x*l3.x + wv.y*l3.y + wv.z*l3.z + wv.w*l3.w;
    }
    if (!side) {
      ssrc[0][k]=a0; ssrc[1][k]=a1; ssrc[2][k]=a2; ssrc[3][k]=a3;
      srcg[(size_t)(row0+0)*EH+k]=a0; srcg[(size_t)(row0+1)*EH+k]=a1;
      srcg[(size_t)(row0+2)*EH+k]=a2; srcg[(size_t)(row0+3)*EH+k]=a3;
    } else {
      tgtb[(size_t)(row0+0)*EH + k] = f2bf_rn(a0);
      tgtb[(size_t)(row0+1)*EH + k] = f2bf_rn(a1);
      tgtb[(size_t)(row0+2)*EH + k] = f2bf_rn(a2);
      tgtb[(size_t)(row0+3)*EH + k] = f2bf_rn(a3);
    }
  }
  __syncthreads();

  // phase 3: Apre = src@Ws^T + b1   (Ws = W1[:, :128]); 256 threads, 2 rows each
  {
    const int kk = tid & 127, half = tid >> 7;
    const float bb = b1[kk];
    float a0 = bb, a1 = bb;
    const float* wr = W1 + (size_t)kk * 384;
    const int r0 = half * 2;
    for (int h4 = 0; h4 < EH; h4 += 4) {
      float4 wv = *(const float4*)(wr + h4);
      float4 l0 = *(const float4*)&ssrc[r0][h4];
      float4 l1 = *(const float4*)&ssrc[r0+1][h4];
      a0 += wv.x*l0.x + wv.y*l0.y + wv.z*l0.z + wv.w*l0.w;
      a1 += wv.x*l1.x + wv.y*l1.y + wv.z*l1.z + wv.w*l1.w;
    }
    apreg[(size_t)(row0+r0)*EH + kk]   = a0;
    apreg[(size_t)(row0+r0+1)*EH + kk] = a1;
  }
}

// -------------------- Kernel B: per-(b,i) MFMA edge row --------------------
// grid 1024 = (b,i), 256 thr = 4 waves. launch_bounds(256,2): the unified
// VGPR+AGPR file means min-4-waves/EU caps combined regs at 128 -> spill cliff
// (R4: 427MB fetch / 290MB write scratch traffic). 2 waves/EU runs clean.
// G'[k][h] = src_i[h]*Wp[k][h] + Wt[k][h], single rn bf16 in swizzled LDS.
// h = tgt @ G'^T + Apre (folded into acc init); sigmoid-gelu; <W2,g>; softsign.
__global__ __launch_bounds__(256, 2) void edge_kernel(
    const float* __restrict__ srcg, const float* __restrict__ apreg,
    const unsigned short* __restrict__ tgtb,
    const float* __restrict__ W1, const float* __restrict__ W2,
    const float* __restrict__ b2, float* __restrict__ out)
{
  __shared__ __align__(16) unsigned short Gs[128 * 128]; // [k][h] swizzled, 32KB
  __shared__ float s_src[128];

  const int tid = threadIdx.x;
  const int l = tid & 63, w = tid >> 6;
  const int blk = blockIdx.x;
  const int b = blk >> 9, i = blk & 511;

  if (tid < 128) s_src[tid] = srcg[(size_t)blk * EH + tid];
  __syncthreads();

  // ---- stage G' (rn bf16, XOR-swizzled rows) ----
  {
    const int k = tid >> 1, h0 = (tid & 1) * 64;
    const float* wpr = W1 + (size_t)k * 384 + 256 + h0;
    const float* wtr = W1 + (size_t)k * 384 + 128 + h0;
    const unsigned int swz = (unsigned int)((k & 15) << 4);
    char* gB = (char*)Gs + k * 256;
    #pragma unroll
    for (int c = 0; c < 64; c += 8) {
      float4 wpa = *(const float4*)(wpr + c);
      float4 wpb = *(const float4*)(wpr + c + 4);
      float4 wta = *(const float4*)(wtr + c);
      float4 wtb = *(const float4*)(wtr + c + 4);
      float4 sa  = *(const float4*)&s_src[h0 + c];
      float4 sb4 = *(const float4*)&s_src[h0 + c + 4];
      short8v hv;
      hv[0] = (short)f2bf_rn(fmaf(sa.x,  wpa.x, wta.x));
      hv[1] = (short)f2bf_rn(fmaf(sa.y,  wpa.y, wta.y));
      hv[2] = (short)f2bf_rn(fmaf(sa.z,  wpa.z, wta.z));
      hv[3] = (short)f2bf_rn(fmaf(sa.w,  wpa.w, wta.w));
      hv[4] = (short)f2bf_rn(fmaf(sb4.x, wpb.x, wtb.x));
      hv[5] = (short)f2bf_rn(fmaf(sb4.y, wpb.y, wtb.y));
      hv[6] = (short)f2bf_rn(fmaf(sb4.z, wpb.z, wtb.z));
      hv[7] = (short)f2bf_rn(fmaf(sb4.w, wpb.w, wtb.w));
      const unsigned int off = ((unsigned int)((h0 + c) * 2)) ^ swz;
      *(short8v*)(gB + off) = hv;
    }
  }
  __syncthreads();

  // per-lane constants: k-column = nt*16 + (l&15)
  const int l15 = l & 15;
  const int hi4 = l >> 4;           // 0..3
  float apv[8], w2v[8];
  #pragma unroll
  for (int nt = 0; nt < 8; ++nt) {
    apv[nt] = apreg[(size_t)blk * EH + nt * 16 + l15];
    w2v[nt] = W2[nt * 16 + l15];
  }
  const float b2s = b2[0];

  const unsigned short* tB = tgtb + (size_t)b * BN * EH;
  float* orow = out + (size_t)blk * BN;

  const int cb = hi4 * 16;          // byte col base within row for B frags
  const unsigned int swzl = (unsigned int)(l15 << 4);

#define LOADA(buf, ks_)                                                        \
  {                                                                            \
    _Pragma("unroll")                                                          \
    for (int m = 0; m < 4; ++m) {                                              \
      const size_t r = (size_t)(jt0 + m * 16 + l15) * EH + (ks_) * 32 + hi4 * 8;\
      buf[m] = *(const short8v*)(tB + r);                                      \
    }                                                                          \
  }

#define MFMA_STEP(buf, ks_)                                                    \
  {                                                                            \
    _Pragma("unroll")                                                          \
    for (int nt = 0; nt < 8; ++nt) {                                           \
      const int rowoff = nt * 4096 + l15 * 256;                                \
      const unsigned int col = ((unsigned int)(((ks_) << 6) | cb)) ^ swzl;     \
      short8v bfr = *(const short8v*)((const char*)Gs + rowoff + col);         \
      _Pragma("unroll")                                                        \
      for (int m = 0; m < 4; ++m)                                              \
        acc[m][nt] = __builtin_amdgcn_mfma_f32_16x16x32_bf16(buf[m], bfr, acc[m][nt], 0, 0, 0); \
    }                                                                          \
  }

  // 2 passes x 4 m-tiles (16 j each) per wave: wave w covers j-tiles w*8 .. w*8+7
  #pragma unroll 1
  for (int p = 0; p < 2; ++p) {
    const int jt0 = (w * 8 + p * 4) * 16;
    f32x4 acc[4][8];
    #pragma unroll
    for (int m = 0; m < 4; ++m)
      #pragma unroll
      for (int nt = 0; nt < 8; ++nt)
        acc[m][nt] = (f32x4){apv[nt], apv[nt], apv[nt], apv[nt]};  // bias folded

    // software-pipelined ks loop: 4 steps, 2-deep A prefetch, no big unroll
    short8v aA[4], aB[4];
    LOADA(aA, 0)
    #pragma unroll 1
    for (int kk = 0; kk < 2; ++kk) {
      const int ks0 = kk * 2;
      LOADA(aB, ks0 + 1)
      MFMA_STEP(aA, ks0)
      if (kk == 0) LOADA(aA, 2)
      MFMA_STEP(aB, ks0 + 1)
    }

    // ---- epilogue: sigmoid-gelu + W2 dot + softsign ----
    #pragma unroll
    for (int m = 0; m < 4; ++m) {
      float ov[4];
      #pragma unroll
      for (int reg = 0; reg < 4; ++reg) {
        float ps = 0.0f;
        #pragma unroll
        for (int nt = 0; nt < 8; ++nt) {
          const float x  = acc[m][nt][reg];
          const float x2 = x * x;
          // gelu(x) = x * sigmoid(1.5957691x + 0.0713548x^3); exp2-folded consts
          const float q = fmaf(x2, -0.10294817f, -2.3022077f);
          const float e = __builtin_amdgcn_exp2f(x * q);
          const float r = __builtin_amdgcn_rcpf(1.0f + e);
          ps = fmaf(w2v[nt], x * r, ps);
        }
        ps += __shfl_xor(ps, 1, 64);
        ps += __shfl_xor(ps, 2, 64);
        ps += __shfl_xor(ps, 4, 64);
        ps += __shfl_xor(ps, 8, 64);
        const float s = ps + b2s;
        ov[reg] = s / (1.0f + fabsf(s));
      }
      if (l15 == 0) {
        const int j0 = jt0 + m * 16 + hi4 * 4;
        float4 o4 = {(j0 + 0 == i) ? 0.0f : ov[0],
                     (j0 + 1 == i) ? 0.0f : ov[1],
                     (j0 + 2 == i) ? 0.0f : ov[2],
                     (j0 + 3 == i) ? 0.0f : ov[3]};
        *(float4*)(orow + j0) = o4;
      }
    }
  }
#undef LOADA
#undef MFMA_STEP
}

// -------------------- launch --------------------
extern "C" void kernel_launch(void* const* d_in, const int* in_sizes, int n_in,
                              void* d_out, int out_size, void* d_ws, size_t ws_size,
                              hipStream_t stream) {
  const float* latent = (const float*)d_in[0];
  const float* sng = (const float*)d_in[1];
  const float* snb = (const float*)d_in[2];
  const float* tng = (const float*)d_in[3];
  const float* tnb = (const float*)d_in[4];
  const float* sW  = (const float*)d_in[5];
  const float* sb  = (const float*)d_in[6];
  const float* tW  = (const float*)d_in[7];
  const float* tb  = (const float*)d_in[8];
  const float* W1  = (const float*)d_in[9];
  const float* b1  = (const float*)d_in[10];
  const float* W2  = (const float*)d_in[11];
  const float* b2  = (const float*)d_in[12];
  float* out = (float*)d_out;

  float* ws = (float*)d_ws;
  float* srcg  = ws;                                      // [1024][128] f32
  float* apreg = ws + 131072;                             // [1024][128] f32
  unsigned short* tgtb = (unsigned short*)(ws + 262144);  // [1024][128] u16

  hipLaunchKernelGGL(prep_kernel, dim3(256), dim3(256), 0, stream,
                     latent, sng, snb, tng, tnb, sW, sb, tW, tb, W1, b1,
                     srcg, apreg, tgtb);
  hipLaunchKernelGGL(edge_kernel, dim3(1024), dim3(256), 0, stream,
                     srcg, apreg, tgtb, W1, W2, b2, out);
}